// Round 1
// baseline (110.267 us; speedup 1.0000x reference)
//
#include <hip/hip_runtime.h>

#define TPB    256
#define CHUNKS 8      // blocks per batch along T
#define NACC   21     // 16 D[i][j] + 4 S1[i] + 1 denom
#define NPERM  24

__constant__ int c_perm[NPERM][4] = {
    {0,1,2,3},{0,1,3,2},{0,2,1,3},{0,2,3,1},{0,3,1,2},{0,3,2,1},
    {1,0,2,3},{1,0,3,2},{1,2,0,3},{1,2,3,0},{1,3,0,2},{1,3,2,0},
    {2,0,1,3},{2,0,3,1},{2,1,0,3},{2,1,3,0},{2,3,0,1},{2,3,1,0},
    {3,0,1,2},{3,0,2,1},{3,1,0,2},{3,1,2,0},{3,2,0,1},{3,2,1,0}
};

// Stage 1: per-(batch, T-chunk) partial sums of the 21 accumulators.
// bce[b,t,i,j] = -lq_i + t_j*(lq_i - lp_i); so we only need
//   D[i][j] = sum_t m * t_j * (lq_i - lp_i)
//   S1[i]   = sum_t m * lq_i
//   dn      = sum_t m
__global__ __launch_bounds__(TPB) void pit_partial(
    const float* __restrict__ pred, const float* __restrict__ target,
    const float* __restrict__ mask, float* __restrict__ partial, int T)
{
    const int b      = blockIdx.x / CHUNKS;
    const int chunk  = blockIdx.x - b * CHUNKS;
    const int tPerBlock = (T + CHUNKS - 1) / CHUNKS;
    const int tid    = threadIdx.x;
    const int base   = chunk * tPerBlock;
    const int tEnd   = min(base + tPerBlock, T);

    const float4* p4  = (const float4*)pred   + (size_t)b * T;
    const float4* t4  = (const float4*)target + (size_t)b * T;
    const float* mrow = mask + (size_t)b * T;

    float D[4][4] = {{0.f,0.f,0.f,0.f},{0.f,0.f,0.f,0.f},
                     {0.f,0.f,0.f,0.f},{0.f,0.f,0.f,0.f}};
    float S1[4] = {0.f,0.f,0.f,0.f};
    float dn = 0.f;

    const float lo = 1e-7f;
    const float hi = 1.0f - 1e-7f;

    for (int t = base + tid; t < tEnd; t += TPB) {
        float4 pv = p4[t];
        float4 tv = t4[t];
        float m   = mrow[t];
        float pp[4] = {pv.x, pv.y, pv.z, pv.w};
        float tt[4] = {tv.x, tv.y, tv.z, tv.w};
        float lp[4], lq[4];
        #pragma unroll
        for (int s = 0; s < 4; ++s) {
            float p = fminf(fmaxf(pp[s], lo), hi);
            lp[s] = __logf(p);
            lq[s] = __logf(1.0f - p);
        }
        dn += m;
        float mt[4];
        #pragma unroll
        for (int j = 0; j < 4; ++j) mt[j] = m * tt[j];
        #pragma unroll
        for (int i = 0; i < 4; ++i) {
            S1[i] = fmaf(m, lq[i], S1[i]);
            float d = lq[i] - lp[i];
            #pragma unroll
            for (int j = 0; j < 4; ++j) D[i][j] = fmaf(d, mt[j], D[i][j]);
        }
    }

    float acc[NACC];
    #pragma unroll
    for (int i = 0; i < 4; ++i)
        #pragma unroll
        for (int j = 0; j < 4; ++j) acc[i * 4 + j] = D[i][j];
    #pragma unroll
    for (int i = 0; i < 4; ++i) acc[16 + i] = S1[i];
    acc[20] = dn;

    // wave-64 butterfly reduction for each accumulator
    #pragma unroll
    for (int k = 0; k < NACC; ++k) {
        float v = acc[k];
        #pragma unroll
        for (int off = 32; off > 0; off >>= 1)
            v += __shfl_xor(v, off, 64);
        acc[k] = v;
    }

    __shared__ float sred[TPB / 64][NACC];
    const int wave = tid >> 6;
    const int lane = tid & 63;
    if (lane == 0) {
        #pragma unroll
        for (int k = 0; k < NACC; ++k) sred[wave][k] = acc[k];
    }
    __syncthreads();
    if (tid < NACC) {
        float v = 0.f;
        #pragma unroll
        for (int w = 0; w < TPB / 64; ++w) v += sred[w][tid];
        partial[(size_t)blockIdx.x * NACC + tid] = v;
    }
}

// Stage 2: one block; thread b sums its CHUNKS partials, builds C[4][4],
// scans the 24 permutations (strict < keeps argmin's first-occurrence rule),
// writes best perm as floats, block-reduces the mean loss.
__global__ __launch_bounds__(128) void pit_final(
    const float* __restrict__ partial, float* __restrict__ out, int B)
{
    const int b = threadIdx.x;
    float minv = 0.f;

    if (b < B) {
        float A[NACC];
        #pragma unroll
        for (int k = 0; k < NACC; ++k) A[k] = 0.f;
        for (int c = 0; c < CHUNKS; ++c) {
            const float* src = partial + (size_t)(b * CHUNKS + c) * NACC;
            #pragma unroll
            for (int k = 0; k < NACC; ++k) A[k] += src[k];
        }
        const float inv = 1.0f / (4.0f * A[20]);   // 1/(S*denom)
        float C[4][4];
        #pragma unroll
        for (int i = 0; i < 4; ++i)
            #pragma unroll
            for (int j = 0; j < 4; ++j)
                C[i][j] = (A[i * 4 + j] - A[16 + i]) * inv;

        minv = 3.4e38f;
        int mini = 0;
        #pragma unroll
        for (int p = 0; p < NPERM; ++p) {
            float v = C[0][c_perm[p][0]] + C[1][c_perm[p][1]]
                    + C[2][c_perm[p][2]] + C[3][c_perm[p][3]];
            if (v < minv) { minv = v; mini = p; }
        }
        #pragma unroll
        for (int i = 0; i < 4; ++i)
            out[1 + b * 4 + i] = (float)c_perm[mini][i];
    }

    // block-reduce sum of per-batch min losses
    float v = minv;
    #pragma unroll
    for (int off = 32; off > 0; off >>= 1)
        v += __shfl_xor(v, off, 64);
    __shared__ float ssum[16];
    const int wave = threadIdx.x >> 6;
    const int nwaves = blockDim.x >> 6;
    if ((threadIdx.x & 63) == 0) ssum[wave] = v;
    __syncthreads();
    if (threadIdx.x == 0) {
        float s = 0.f;
        for (int w = 0; w < nwaves; ++w) s += ssum[w];
        out[0] = s / (float)B;
    }
}

extern "C" void kernel_launch(void* const* d_in, const int* in_sizes, int n_in,
                              void* d_out, int out_size, void* d_ws, size_t ws_size,
                              hipStream_t stream)
{
    const float* pred   = (const float*)d_in[0];
    const float* target = (const float*)d_in[1];
    const float* mask   = (const float*)d_in[2];
    float* out     = (float*)d_out;
    float* partial = (float*)d_ws;   // B*CHUNKS*NACC floats = 86 KB

    const int B = (out_size - 1) / 4;      // out = [loss] + [B,4] perms
    const int T = in_sizes[2] / B;         // mask is [B,T]

    pit_partial<<<B * CHUNKS, TPB, 0, stream>>>(pred, target, mask, partial, T);
    pit_final<<<1, 128, 0, stream>>>(partial, out, B);
}